// Round 6
// baseline (184.978 us; speedup 1.0000x reference)
//
#include <hip/hip_runtime.h>

typedef short short8 __attribute__((ext_vector_type(8)));
typedef float f32x4 __attribute__((ext_vector_type(4)));

#define EPS 0.012f   // > 4x worst-case bf16-split dist error

__device__ __forceinline__ unsigned short rne_bf16(float v) {
    unsigned u = __float_as_uint(v);
    unsigned r = u + 0x7FFFu + ((u >> 16) & 1u);
    return (unsigned short)(r >> 16);
}
__device__ __forceinline__ float bf16_to_f(unsigned short h) {
    return __uint_as_float(((unsigned)h) << 16);
}
// xs swizzle at float4 granularity: float index = row*64 + (d ^ ((row&15)<<2))
__device__ __forceinline__ int xsw(int row, int d4) {
    return row * 64 + (d4 ^ ((row & 15) << 2));
}

#define MFMA(a,b,c) __builtin_amdgcn_mfma_f32_16x16x32_bf16((a),(b),(c),0,0,0)

// ---- prep: codebook fp32 -> bf16 hi/lo (fragment-ready linear layout) + norms ----
__global__ __launch_bounds__(64) void prep_kernel(
    const float* __restrict__ emb, unsigned short* __restrict__ whi,
    unsigned short* __restrict__ wlo, float* __restrict__ wee)
{
    const int k = blockIdx.x * 64 + threadIdx.x;   // 512 rows
    const float* src = emb + k * 64;
    float nrm = 0.f;
    #pragma unroll
    for (int g = 0; g < 8; ++g) {
        float4 v0 = *(const float4*)(src + g * 8);
        float4 v1 = *(const float4*)(src + g * 8 + 4);
        float vv[8] = {v0.x, v0.y, v0.z, v0.w, v1.x, v1.y, v1.z, v1.w};
        short8 h8, l8;
        #pragma unroll
        for (int i = 0; i < 8; ++i) {
            nrm = fmaf(vv[i], vv[i], nrm);
            unsigned short hb = rne_bf16(vv[i]);
            h8[i] = (short)hb;
            l8[i] = (short)rne_bf16(vv[i] - bf16_to_f(hb));
        }
        *(short8*)(whi + k * 64 + g * 8) = h8;
        *(short8*)(wlo + k * 64 + g * 8) = l8;
    }
    wee[k] = nrm;
}

__global__ __launch_bounds__(256, 5) void vq_kernel(
    const float* __restrict__ x, const float* __restrict__ emb,
    const unsigned short* __restrict__ whi, const unsigned short* __restrict__ wlo,
    const float* __restrict__ wee,
    float* __restrict__ out_q, float* __restrict__ out_enc,
    float* __restrict__ out_dist, float* __restrict__ out_loss)
{
    __shared__ __align__(16) float xs[64 * 64];   // fp32 x tile, float4-swizzled (16 KB)
    __shared__ float ee_s[512];
    __shared__ float xpart[4][64];
    __shared__ float xx_s[64];
    __shared__ int   enc_s[64];
    __shared__ float red_s[4];

    const int t   = threadIdx.x;
    const int bid = blockIdx.x;              // 2048 blocks x 64 rows (rows = w; b,h fixed)
    const int n_base = bid * 64;
    const size_t xbase = (size_t)(bid >> 6) * 262144 + (size_t)(bid & 63) * 64;
    const int l  = t & 63;
    const int wv = t >> 6;                   // 4 waves; wave owns rows wv*16..+15

    // ---- stage x tile fp32 + ee norms into LDS ----
    {
        const int w  = t & 63;
        const int c0 = t >> 6;               // quads c0, c0+4, c0+8, c0+12
        const size_t gb = xbase + w;
        float part = 0.f;
        #pragma unroll
        for (int cc = 0; cc < 4; ++cc) {
            int d4 = (c0 + cc * 4) * 4;
            float4 v;
            v.x = x[gb + (size_t)(d4 + 0) * 4096];
            v.y = x[gb + (size_t)(d4 + 1) * 4096];
            v.z = x[gb + (size_t)(d4 + 2) * 4096];
            v.w = x[gb + (size_t)(d4 + 3) * 4096];
            part = fmaf(v.x, v.x, part); part = fmaf(v.y, v.y, part);
            part = fmaf(v.z, v.z, part); part = fmaf(v.w, v.w, part);
            *(float4*)&xs[xsw(w, d4)] = v;
        }
        xpart[c0][w] = part;
        ee_s[t]       = wee[t];
        ee_s[t + 256] = wee[t + 256];
    }
    __syncthreads();
    if (t < 64) xx_s[t] = (xpart[0][t] + xpart[1][t]) + (xpart[2][t] + xpart[3][t]);

    // ---- A fragments from LDS, bf16 hi/lo split in registers ----
    // A layout (16x32): row = lane&15, k = (lane>>4)*8 + i   (validated R4/R5)
    const int arow = wv * 16 + (l & 15);
    const int ad0  = (l >> 4) * 8;
    short8 ahi0, ahi1, alo0, alo1;
    {
        float va[16];
        *(float4*)&va[0]  = *(const float4*)&xs[xsw(arow, ad0)];
        *(float4*)&va[4]  = *(const float4*)&xs[xsw(arow, ad0 + 4)];
        *(float4*)&va[8]  = *(const float4*)&xs[xsw(arow, ad0 + 32)];
        *(float4*)&va[12] = *(const float4*)&xs[xsw(arow, ad0 + 36)];
        #pragma unroll
        for (int i = 0; i < 8; ++i) {
            unsigned short hb = rne_bf16(va[i]);
            ahi0[i] = (short)hb; alo0[i] = (short)rne_bf16(va[i] - bf16_to_f(hb));
            unsigned short hb2 = rne_bf16(va[8 + i]);
            ahi1[i] = (short)hb2; alo1[i] = (short)rne_bf16(va[8 + i] - bf16_to_f(hb2));
        }
    }
    __syncthreads();   // xx_s ready

    // C/D layout: col = lane&15 (k), row = (lane>>4)*4 + reg   (validated R4/R5)
    const int rlw0 = (l >> 4) * 4;
    const int n0   = n_base + wv * 16 + rlw0;
    float xx4[4];
    #pragma unroll
    for (int r = 0; r < 4; ++r) xx4[r] = xx_s[wv * 16 + rlw0 + r];

    float m1[4], m2[4]; int k1[4];
    #pragma unroll
    for (int r = 0; r < 4; ++r) { m1[r] = 3.4e38f; m2[r] = 3.4e38f; k1[r] = 0; }

    float* dbase = out_dist + (size_t)n0 * 512 + (l & 15);
    const short8* Hbase = (const short8*)whi;
    const short8* Lbase = (const short8*)wlo;
    const int bidx = (l & 15) * 8 + (l >> 4);   // per-lane B-frag base (short8 units)

    // ---- main loop: 32 k-tiles, B frags straight from L2, zero barriers ----
    #pragma unroll 4
    for (int kt = 0; kt < 32; ++kt) {
        const int o = kt * 128 + bidx;
        short8 bh0 = Hbase[o];
        short8 bh1 = Hbase[o + 4];
        short8 bl0 = Lbase[o];
        short8 bl1 = Lbase[o + 4];
        f32x4 accA = {0.f, 0.f, 0.f, 0.f};
        f32x4 accB = {0.f, 0.f, 0.f, 0.f};
        accA = MFMA(ahi0, bh0, accA);
        accB = MFMA(ahi1, bh1, accB);
        accA = MFMA(alo0, bh0, accA);
        accB = MFMA(alo1, bh1, accB);
        accA = MFMA(ahi0, bl0, accA);
        accB = MFMA(ahi1, bl1, accB);
        const int kl = kt * 16 + (l & 15);
        float eek = ee_s[kl];
        float* dp = dbase + kt * 16;
        #pragma unroll
        for (int r = 0; r < 4; ++r) {
            float dist = fmaf(accA[r] + accB[r], -2.f, xx4[r] + eek);
            dp[(size_t)r * 512] = dist;
            if (dist < m1[r]) { m2[r] = m1[r]; m1[r] = dist; k1[r] = kl; }   // kt ascending
            else if (dist < m2[r]) m2[r] = dist;
        }
    }

    __syncthreads();   // drains vmcnt: own dist stores visible for refine readback

    // ---- per-row argmin + rare candidate-only fp64 refinement (proven R5) ----
    float lacc = 0.f;
    {
        const unsigned long long gmask = 0xFFFFull << ((l >> 4) << 4);
        #pragma unroll 1
        for (int r = 0; r < 4; ++r) {
            float bv = m1[r]; int bk = k1[r];
            #pragma unroll
            for (int m = 1; m < 16; m <<= 1) {
                float ov = __shfl_xor(bv, m, 64);
                int   ok = __shfl_xor(bk, m, 64);
                if (ov < bv || (ov == bv && ok < bk)) { bv = ov; bk = ok; }
            }
            float thr = bv + EPS;
            unsigned long long b1 = __ballot(m1[r] <= thr);
            unsigned long long b2 = __ballot(m2[r] <= thr);
            int enc = bk; float lossv = bv;
            if (__popcll(b1 & gmask) > 1 || (b2 & gmask) != 0ULL) {
                const int rowg = wv * 16 + rlw0 + r;
                const float* drow = out_dist + (size_t)(n_base + rowg) * 512 + (l & 15) * 32;
                double bestv = 1e300; int bestk = 0x7fffffff;
                #pragma unroll 1
                for (int c4 = 0; c4 < 8; ++c4) {
                    float4 dv = *(const float4*)(drow + c4 * 4);
                    float dvv[4] = {dv.x, dv.y, dv.z, dv.w};
                    #pragma unroll 1
                    for (int j = 0; j < 4; ++j) {
                        if (dvv[j] <= thr) {
                            int k = (l & 15) * 32 + c4 * 4 + j;
                            const float* er = emb + k * 64;
                            double s = 0.0;
                            #pragma unroll 4
                            for (int d = 0; d < 64; d += 4) {
                                float4 ev = *(const float4*)(er + d);
                                float4 xv = *(const float4*)&xs[xsw(rowg, d)];
                                double d0_ = (double)xv.x - (double)ev.x;
                                double d1_ = (double)xv.y - (double)ev.y;
                                double d2_ = (double)xv.z - (double)ev.z;
                                double d3_ = (double)xv.w - (double)ev.w;
                                s += d0_ * d0_ + d1_ * d1_ + d2_ * d2_ + d3_ * d3_;
                            }
                            if (s < bestv) { bestv = s; bestk = k; }  // ascending k, strict <
                        }
                    }
                }
                #pragma unroll
                for (int m = 1; m < 16; m <<= 1) {
                    double ov = __shfl_xor(bestv, m, 64);
                    int   ok  = __shfl_xor(bestk, m, 64);
                    if (ov < bestv || (ov == bestv && ok < bestk)) { bestv = ov; bestk = ok; }
                }
                enc = bestk;
                if ((l & 15) == 0 && enc != bk)
                    lossv = out_dist[(size_t)(n_base + rowg) * 512 + enc];
            }
            if ((l & 15) == 0) {
                enc_s[wv * 16 + rlw0 + r] = enc;
                out_enc[n0 + r] = (float)enc;
                lacc += lossv;   // row's (q-x)^2 sum == dist[row][enc]
            }
        }
    }
    #pragma unroll
    for (int m = 32; m >= 1; m >>= 1) lacc += __shfl_down(lacc, m, 64);
    if (l == 0) red_s[wv] = lacc;
    __syncthreads();
    if (t == 0)
        atomicAdd(out_loss, (red_s[0] + red_s[1] + red_s[2] + red_s[3]) * (1.0f / 8388608.0f));

    // ---- quantized gather (codebook L2-resident) + coalesced store ----
    {
        const int w  = t & 63;
        const int dg = t >> 6;               // 0..3 -> d = dg*16..+15
        const int e  = enc_s[w];
        const float* er = emb + e * 64 + dg * 16;
        float* qp = out_q + xbase + (size_t)(dg * 16) * 4096 + w;
        #pragma unroll
        for (int qi = 0; qi < 4; ++qi) {
            float4 q4 = *(const float4*)(er + qi * 4);
            qp[(size_t)(qi * 4 + 0) * 4096] = q4.x;
            qp[(size_t)(qi * 4 + 1) * 4096] = q4.y;
            qp[(size_t)(qi * 4 + 2) * 4096] = q4.z;
            qp[(size_t)(qi * 4 + 3) * 4096] = q4.w;
        }
    }
}

extern "C" void kernel_launch(void* const* d_in, const int* in_sizes, int n_in,
                              void* d_out, int out_size, void* d_ws, size_t ws_size,
                              hipStream_t stream) {
    const float* x   = (const float*)d_in[0];   // [32,64,64,64]
    const float* emb = (const float*)d_in[1];   // [512,64]

    float* out_q    = (float*)d_out;            // 8388608
    float* out_enc  = out_q + 8388608;          // 131072
    float* out_dist = out_enc + 131072;         // 67108864
    float* out_loss = out_dist + 67108864;      // 1

    unsigned short* whi = (unsigned short*)d_ws;        // 512*64 bf16 hi   (64 KB)
    unsigned short* wlo = whi + 32768;                  // 512*64 bf16 lo   (64 KB)
    float*          wee = (float*)(whi + 65536);        // 512 norms        (2 KB)

    hipMemsetAsync(out_loss, 0, sizeof(float), stream);
    prep_kernel<<<8, 64, 0, stream>>>(emb, whi, wlo, wee);
    vq_kernel<<<2048, 256, 0, stream>>>(x, emb, whi, wlo, wee,
                                        out_q, out_enc, out_dist, out_loss);
}

// Round 7
// 130.049 us; speedup vs baseline: 1.4224x; 1.4224x over previous
//
#include <hip/hip_runtime.h>

typedef short short8 __attribute__((ext_vector_type(8)));
typedef float f32x4 __attribute__((ext_vector_type(4)));

#define EPS 0.012f   // > 4x worst-case bf16-split dist error

__device__ __forceinline__ unsigned short rne_bf16(float v) {
    unsigned u = __float_as_uint(v);
    unsigned r = u + 0x7FFFu + ((u >> 16) & 1u);
    return (unsigned short)(r >> 16);
}
__device__ __forceinline__ float bf16_to_f(unsigned short h) {
    return __uint_as_float(((unsigned)h) << 16);
}
// xs swizzle at float4 granularity: float index = row*64 + (d ^ ((row&15)<<2))
__device__ __forceinline__ int xsw(int row, int d4) {
    return row * 64 + (d4 ^ ((row & 15) << 2));
}

#define MFMA(a,b,c) __builtin_amdgcn_mfma_f32_16x16x32_bf16((a),(b),(c),0,0,0)

// ---- prep: codebook fp32 -> bf16 hi/lo (linear [k][d]) + fp32 norms ----
__global__ __launch_bounds__(64) void prep_kernel(
    const float* __restrict__ emb, unsigned short* __restrict__ whi,
    unsigned short* __restrict__ wlo, float* __restrict__ wee)
{
    const int k = blockIdx.x * 64 + threadIdx.x;   // 512 rows
    const float* src = emb + k * 64;
    float nrm = 0.f;
    #pragma unroll
    for (int g = 0; g < 8; ++g) {
        float4 v0 = *(const float4*)(src + g * 8);
        float4 v1 = *(const float4*)(src + g * 8 + 4);
        float vv[8] = {v0.x, v0.y, v0.z, v0.w, v1.x, v1.y, v1.z, v1.w};
        short8 h8, l8;
        #pragma unroll
        for (int i = 0; i < 8; ++i) {
            nrm = fmaf(vv[i], vv[i], nrm);
            unsigned short hb = rne_bf16(vv[i]);
            h8[i] = (short)hb;
            l8[i] = (short)rne_bf16(vv[i] - bf16_to_f(hb));
        }
        *(short8*)(whi + k * 64 + g * 8) = h8;
        *(short8*)(wlo + k * 64 + g * 8) = l8;
    }
    wee[k] = nrm;
}

__global__ __launch_bounds__(1024, 4) void vq_kernel(
    const float* __restrict__ x, const float* __restrict__ emb,
    const unsigned short* __restrict__ whi, const unsigned short* __restrict__ wlo,
    const float* __restrict__ wee,
    float* __restrict__ out_q, float* __restrict__ out_enc,
    float* __restrict__ out_dist, float* __restrict__ out_loss)
{
    __shared__ __align__(16) unsigned short ehi[512 * 64];  // 64 KB, XOR-swizzled
    __shared__ __align__(16) unsigned short elo[512 * 64];  // 64 KB
    __shared__ __align__(16) float xs[64 * 64];             // 16 KB, reused 4x
    __shared__ float ee_s[512];
    __shared__ float xpart[16][64];
    __shared__ float xx_s[256];
    __shared__ int   enc_s[256];
    __shared__ float red_s[16];

    const int t   = threadIdx.x;
    const int bid = blockIdx.x;              // 512 blocks x 256 rows (row = hh*64 + w)
    const int n_base = bid * 256;
    const int b   = bid >> 4;
    const int h0  = (bid & 15) * 4;
    const size_t xb0 = (size_t)b * 262144 + (size_t)h0 * 64;  // + d*4096 + hh*64 + w
    const int l  = t & 63;
    const int wv = t >> 6;                   // 16 waves; wave owns rows wv*16..+15

    // ---- stage codebook (already bf16 hi/lo) into LDS, XOR-swizzled; + norms ----
    if (t < 512) ee_s[t] = wee[t];
    #pragma unroll
    for (int it = 0; it < 4; ++it) {
        int flat = t + it * 1024;            // short8 unit 0..4095
        int kr = flat >> 3, d0 = (flat & 7) * 8;
        short8 h8 = *(const short8*)(whi + flat * 8);   // coalesced 16B
        short8 l8 = *(const short8*)(wlo + flat * 8);
        int idx = kr * 64 + (d0 ^ ((kr & 7) << 3));
        *(short8*)&ehi[idx] = h8;
        *(short8*)&elo[idx] = l8;
    }

    // ---- x prologue: 4 groups of 64 rows through reusable xs; build A-frags ----
    // A layout (16x32): row = lane&15, k = (lane>>4)*8 + i   (validated R4-R6)
    short8 ahi0, ahi1, alo0, alo1;
    const int gown = wv >> 2;                // group this wave's rows belong to
    #pragma unroll 1
    for (int g = 0; g < 4; ++g) {
        __syncthreads();                     // xs safe to overwrite
        {
            const int w = t & 63, c0 = t >> 6;          // c0: 0..15 -> d4 = c0*4
            const size_t gb = xb0 + (size_t)g * 64 + w;
            float4 v;
            v.x = x[gb + (size_t)(c0 * 4 + 0) * 4096];
            v.y = x[gb + (size_t)(c0 * 4 + 1) * 4096];
            v.z = x[gb + (size_t)(c0 * 4 + 2) * 4096];
            v.w = x[gb + (size_t)(c0 * 4 + 3) * 4096];
            float p = fmaf(v.x, v.x, 0.f); p = fmaf(v.y, v.y, p);
            p = fmaf(v.z, v.z, p); p = fmaf(v.w, v.w, p);
            xpart[c0][w] = p;
            *(float4*)&xs[xsw(w, c0 * 4)] = v;
        }
        __syncthreads();                     // xs + xpart ready
        if (t < 64) {
            float s = 0.f;
            #pragma unroll
            for (int c = 0; c < 16; ++c) s += xpart[c][t];
            xx_s[g * 64 + t] = s;
        }
        if (gown == g) {
            const int arow = (wv & 3) * 16 + (l & 15);
            const int ad0  = (l >> 4) * 8;
            float va[16];
            *(float4*)&va[0]  = *(const float4*)&xs[xsw(arow, ad0)];
            *(float4*)&va[4]  = *(const float4*)&xs[xsw(arow, ad0 + 4)];
            *(float4*)&va[8]  = *(const float4*)&xs[xsw(arow, ad0 + 32)];
            *(float4*)&va[12] = *(const float4*)&xs[xsw(arow, ad0 + 36)];
            #pragma unroll
            for (int i = 0; i < 8; ++i) {
                unsigned short hb = rne_bf16(va[i]);
                ahi0[i] = (short)hb; alo0[i] = (short)rne_bf16(va[i] - bf16_to_f(hb));
                unsigned short hb2 = rne_bf16(va[8 + i]);
                ahi1[i] = (short)hb2; alo1[i] = (short)rne_bf16(va[8 + i] - bf16_to_f(hb2));
            }
        }
    }
    __syncthreads();   // xx_s (g=3) + all LDS staging complete

    // C/D layout: col = lane&15 (k), row = (lane>>4)*4 + reg   (validated R4-R6)
    const int rlw0 = (l >> 4) * 4;
    const int row0 = wv * 16 + rlw0;         // local rows row0..row0+3
    const int n0   = n_base + row0;
    float xx4[4];
    #pragma unroll
    for (int r = 0; r < 4; ++r) xx4[r] = xx_s[row0 + r];

    float m1[4], m2[4]; int k1[4];
    #pragma unroll
    for (int r = 0; r < 4; ++r) { m1[r] = 3.4e38f; m2[r] = 3.4e38f; k1[r] = 0; }

    float* dbase = out_dist + (size_t)n0 * 512 + (l & 15);
    const int bd0 = (l >> 4) * 8;

    // ---- main loop: 32 k-tiles, B from LDS (lgkmcnt), stores free-flow, 0 barriers ----
    #pragma unroll 4
    for (int kt = 0; kt < 32; ++kt) {
        const int kl  = kt * 16 + (l & 15);
        const int bix = kl * 64;
        const int bsw = (kl & 7) << 3;
        short8 bh0 = *(short8*)&ehi[bix + (bd0 ^ bsw)];
        short8 bh1 = *(short8*)&ehi[bix + ((bd0 + 32) ^ bsw)];
        short8 bl0 = *(short8*)&elo[bix + (bd0 ^ bsw)];
        short8 bl1 = *(short8*)&elo[bix + ((bd0 + 32) ^ bsw)];
        f32x4 accA = {0.f, 0.f, 0.f, 0.f};
        f32x4 accB = {0.f, 0.f, 0.f, 0.f};
        accA = MFMA(ahi0, bh0, accA);
        accB = MFMA(ahi1, bh1, accB);
        accA = MFMA(alo0, bh0, accA);
        accB = MFMA(alo1, bh1, accB);
        accA = MFMA(ahi0, bl0, accA);
        accB = MFMA(ahi1, bl1, accB);
        float eek = ee_s[kl];
        float* dp = dbase + kt * 16;
        #pragma unroll
        for (int r = 0; r < 4; ++r) {
            float dist = fmaf(accA[r] + accB[r], -2.f, xx4[r] + eek);
            dp[(size_t)r * 512] = dist;
            if (dist < m1[r]) { m2[r] = m1[r]; m1[r] = dist; k1[r] = kl; }   // kt ascending
            else if (dist < m2[r]) m2[r] = dist;
        }
    }

    __syncthreads();   // drains vmcnt: dist stores visible for refine readback

    // ---- per-row argmin + rare candidate-only fp64 refinement (proven R5) ----
    float lacc = 0.f;
    {
        const unsigned long long gmask = 0xFFFFull << ((l >> 4) << 4);
        #pragma unroll 1
        for (int r = 0; r < 4; ++r) {
            float bv = m1[r]; int bk = k1[r];
            #pragma unroll
            for (int m = 1; m < 16; m <<= 1) {
                float ov = __shfl_xor(bv, m, 64);
                int   ok = __shfl_xor(bk, m, 64);
                if (ov < bv || (ov == bv && ok < bk)) { bv = ov; bk = ok; }
            }
            float thr = bv + EPS;
            unsigned long long b1 = __ballot(m1[r] <= thr);
            unsigned long long b2 = __ballot(m2[r] <= thr);
            int enc = bk; float lossv = bv;
            if (__popcll(b1 & gmask) > 1 || (b2 & gmask) != 0ULL) {
                const int rowg = row0 + r;               // local row 0..255
                const float* drow = out_dist + (size_t)(n_base + rowg) * 512 + (l & 15) * 32;
                const float* xcol = x + xb0 + (size_t)(rowg >> 6) * 64 + (rowg & 63);
                double bestv = 1e300; int bestk = 0x7fffffff;
                #pragma unroll 1
                for (int c4 = 0; c4 < 8; ++c4) {
                    float4 dv = *(const float4*)(drow + c4 * 4);
                    float dvv[4] = {dv.x, dv.y, dv.z, dv.w};
                    #pragma unroll 1
                    for (int j = 0; j < 4; ++j) {
                        if (dvv[j] <= thr) {
                            int k = (l & 15) * 32 + c4 * 4 + j;
                            const float* er = emb + k * 64;
                            double s = 0.0;
                            #pragma unroll 4
                            for (int d = 0; d < 64; ++d) {
                                double df = (double)xcol[(size_t)d * 4096] - (double)er[d];
                                s += df * df;
                            }
                            if (s < bestv) { bestv = s; bestk = k; }  // ascending k, strict <
                        }
                    }
                }
                #pragma unroll
                for (int m = 1; m < 16; m <<= 1) {
                    double ov = __shfl_xor(bestv, m, 64);
                    int   ok  = __shfl_xor(bestk, m, 64);
                    if (ov < bestv || (ov == bestv && ok < bestk)) { bestv = ov; bestk = ok; }
                }
                enc = bestk;
                if ((l & 15) == 0 && enc != bk)
                    lossv = out_dist[(size_t)(n_base + rowg) * 512 + enc];
            }
            if ((l & 15) == 0) {
                enc_s[row0 + r] = enc;
                out_enc[n0 + r] = (float)enc;
                lacc += lossv;   // row's (q-x)^2 sum == dist[row][enc]
            }
        }
    }
    #pragma unroll
    for (int m = 32; m >= 1; m >>= 1) lacc += __shfl_down(lacc, m, 64);
    if (l == 0) red_s[wv] = lacc;
    __syncthreads();
    if (t == 0) {
        float tot = 0.f;
        #pragma unroll
        for (int i = 0; i < 16; ++i) tot += red_s[i];
        atomicAdd(out_loss, tot * (1.0f / 8388608.0f));
    }

    // ---- quantized gather (codebook L2-resident) + coalesced store ----
    {
        const int w  = t & 63;
        const int qq = t >> 6;               // 0..15
        const int hh = qq & 3;
        const int dg = qq >> 2;              // d = dg*16..+15
        const int row = hh * 64 + w;
        const int e  = enc_s[row];
        const float* er = emb + e * 64 + dg * 16;
        float* qp = out_q + xb0 + (size_t)(dg * 16) * 4096 + hh * 64 + w;
        #pragma unroll
        for (int qi = 0; qi < 4; ++qi) {
            float4 q4 = *(const float4*)(er + qi * 4);
            qp[(size_t)(qi * 4 + 0) * 4096] = q4.x;
            qp[(size_t)(qi * 4 + 1) * 4096] = q4.y;
            qp[(size_t)(qi * 4 + 2) * 4096] = q4.z;
            qp[(size_t)(qi * 4 + 3) * 4096] = q4.w;
        }
    }
}

extern "C" void kernel_launch(void* const* d_in, const int* in_sizes, int n_in,
                              void* d_out, int out_size, void* d_ws, size_t ws_size,
                              hipStream_t stream) {
    const float* x   = (const float*)d_in[0];   // [32,64,64,64]
    const float* emb = (const float*)d_in[1];   // [512,64]

    float* out_q    = (float*)d_out;            // 8388608
    float* out_enc  = out_q + 8388608;          // 131072
    float* out_dist = out_enc + 131072;         // 67108864
    float* out_loss = out_dist + 67108864;      // 1

    unsigned short* whi = (unsigned short*)d_ws;        // 512*64 bf16 hi   (64 KB)
    unsigned short* wlo = whi + 32768;                  // 512*64 bf16 lo   (64 KB)
    float*          wee = (float*)(whi + 65536);        // 512 norms        (2 KB)

    hipMemsetAsync(out_loss, 0, sizeof(float), stream);
    prep_kernel<<<8, 64, 0, stream>>>(emb, whi, wlo, wee);
    vq_kernel<<<512, 1024, 0, stream>>>(x, emb, whi, wlo, wee,
                                        out_q, out_enc, out_dist, out_loss);
}

// Round 8
// 117.476 us; speedup vs baseline: 1.5746x; 1.1070x over previous
//
#include <hip/hip_runtime.h>

typedef short short8 __attribute__((ext_vector_type(8)));
typedef float f32x4 __attribute__((ext_vector_type(4)));

#define EPS 0.012f   // > 4x worst-case bf16-split dist error

__device__ __forceinline__ unsigned short rne_bf16(float v) {
    unsigned u = __float_as_uint(v);
    unsigned r = u + 0x7FFFu + ((u >> 16) & 1u);
    return (unsigned short)(r >> 16);
}
__device__ __forceinline__ float bf16_to_f(unsigned short h) {
    return __uint_as_float(((unsigned)h) << 16);
}

#define MFMA(a,b,c) __builtin_amdgcn_mfma_f32_16x16x32_bf16((a),(b),(c),0,0,0)

// ---- prep: codebook fp32 -> bf16 hi/lo (linear [k][d]) + fp32 norms ----
__global__ __launch_bounds__(64) void prep_kernel(
    const float* __restrict__ emb, unsigned short* __restrict__ whi,
    unsigned short* __restrict__ wlo, float* __restrict__ wee)
{
    const int k = blockIdx.x * 64 + threadIdx.x;   // 512 rows
    const float* src = emb + k * 64;
    float nrm = 0.f;
    #pragma unroll
    for (int g = 0; g < 8; ++g) {
        float4 v0 = *(const float4*)(src + g * 8);
        float4 v1 = *(const float4*)(src + g * 8 + 4);
        float vv[8] = {v0.x, v0.y, v0.z, v0.w, v1.x, v1.y, v1.z, v1.w};
        short8 h8, l8;
        #pragma unroll
        for (int i = 0; i < 8; ++i) {
            nrm = fmaf(vv[i], vv[i], nrm);
            unsigned short hb = rne_bf16(vv[i]);
            h8[i] = (short)hb;
            l8[i] = (short)rne_bf16(vv[i] - bf16_to_f(hb));
        }
        *(short8*)(whi + k * 64 + g * 8) = h8;
        *(short8*)(wlo + k * 64 + g * 8) = l8;
    }
    wee[k] = nrm;
}

__global__ __launch_bounds__(256, 4) void vq_kernel(
    const float* __restrict__ x, const float* __restrict__ emb,
    const unsigned short* __restrict__ whi, const unsigned short* __restrict__ wlo,
    const float* __restrict__ wee,
    float* __restrict__ out_q, float* __restrict__ out_enc,
    float* __restrict__ out_dist, float* __restrict__ out_loss)
{
    __shared__ __align__(16) unsigned short ehi[2][64 * 64];  // 16 KB dbuf, swizzled
    __shared__ __align__(16) unsigned short elo[2][64 * 64];  // 16 KB
    __shared__ float ee_s[512];
    __shared__ int   enc_s[64];
    __shared__ float red_s[4];

    const int t   = threadIdx.x;
    const int bid = blockIdx.x;              // 2048 blocks x 64 rows (rows = w)
    const int n_base = bid * 64;
    const size_t xbase = (size_t)(bid >> 6) * 262144 + (size_t)(bid & 63) * 64;
    const int l  = t & 63;
    const int wv = t >> 6;                   // 4 waves; wave owns rows wv*16..+15

    ee_s[t]       = wee[t];
    ee_s[t + 256] = wee[t + 256];

    // ---- x prologue: per-lane fragment load straight from global, no LDS ----
    // B layout (32x16): col = lane&15 (x row), d = (lane>>4)*8 + i  (+32 for frag1)
    const int myw = wv * 16 + (l & 15);      // this lane's row (= w)
    const int g8  = (l >> 4) * 8;
    float va[16];
    {
        const float* xp = x + xbase + myw;
        #pragma unroll
        for (int i = 0; i < 8; ++i) {
            va[i]     = xp[(size_t)(g8 + i) * 4096];
            va[8 + i] = xp[(size_t)(g8 + 32 + i) * 4096];
        }
    }
    short8 xhi0, xhi1, xlo0, xlo1;
    float xx = 0.f;
    #pragma unroll
    for (int i = 0; i < 8; ++i) {
        xx = fmaf(va[i], va[i], xx);
        xx = fmaf(va[8 + i], va[8 + i], xx);
        unsigned short hb = rne_bf16(va[i]);
        xhi0[i] = (short)hb; xlo0[i] = (short)rne_bf16(va[i] - bf16_to_f(hb));
        unsigned short hb2 = rne_bf16(va[8 + i]);
        xhi1[i] = (short)hb2; xlo1[i] = (short)rne_bf16(va[8 + i] - bf16_to_f(hb2));
    }
    xx += __shfl_xor(xx, 16, 64);            // 4 lane-groups cover disjoint d-ranges
    xx += __shfl_xor(xx, 32, 64);

    // ---- chunked double-buffered codebook staging (T14 load-early/write-late) ----
    short8 sh[2], sl[2];
    #define STAGE_LOAD(c) {                                                   \
        _Pragma("unroll")                                                     \
        for (int p = 0; p < 2; ++p) {                                         \
            int u = t + p * 256;                                              \
            int kr = u >> 3, d0 = (u & 7) * 8;                                \
            sh[p] = *(const short8*)(whi + (size_t)(((c) * 64 + kr) * 64 + d0)); \
            sl[p] = *(const short8*)(wlo + (size_t)(((c) * 64 + kr) * 64 + d0)); \
        } }
    #define STAGE_WRITE(bufi) {                                               \
        _Pragma("unroll")                                                     \
        for (int p = 0; p < 2; ++p) {                                         \
            int u = t + p * 256;                                              \
            int kr = u >> 3, d0 = (u & 7) * 8;                                \
            int idx = kr * 64 + (d0 ^ ((kr & 7) << 3));                       \
            *(short8*)&ehi[bufi][idx] = sh[p];                                \
            *(short8*)&elo[bufi][idx] = sl[p];                                \
        } }

    STAGE_LOAD(0); STAGE_WRITE(0);
    float m1 = 3.4e38f, m2 = 3.4e38f; int k1 = 0;
    const int colb = (l >> 4) * 4;           // this lane's k sub-base in a tile
    float* drow = out_dist + (size_t)(n_base + myw) * 512;
    __syncthreads();

    // ---- main loop: 8 chunks x 4 k-tiles; A=codebook from LDS, B=x in regs ----
    #pragma unroll 1
    for (int c = 0; c < 8; ++c) {
        if (c < 7) STAGE_LOAD(c + 1);        // HBM/L2 latency hides under compute
        const int bufi = c & 1;
        #pragma unroll
        for (int kti = 0; kti < 4; ++kti) {
            const int krl = kti * 16 + (l & 15);     // codebook row in chunk (A row)
            const int sw  = (krl & 7) << 3;
            const int bix = krl * 64;
            short8 ch0 = *(short8*)&ehi[bufi][bix + (g8 ^ sw)];
            short8 ch1 = *(short8*)&ehi[bufi][bix + ((g8 + 32) ^ sw)];
            short8 cl0 = *(short8*)&elo[bufi][bix + (g8 ^ sw)];
            short8 cl1 = *(short8*)&elo[bufi][bix + ((g8 + 32) ^ sw)];
            f32x4 accA = {0.f, 0.f, 0.f, 0.f};
            f32x4 accB = {0.f, 0.f, 0.f, 0.f};
            accA = MFMA(ch0, xhi0, accA);
            accB = MFMA(ch1, xhi1, accB);
            accA = MFMA(cl0, xhi0, accA);
            accB = MFMA(cl1, xhi1, accB);
            accA = MFMA(ch0, xlo0, accA);
            accB = MFMA(ch1, xlo1, accB);
            const int kb = c * 64 + kti * 16 + colb;   // lane's 4 k's: kb..kb+3
            float4 ee4 = *(const float4*)&ee_s[kb];
            float eev[4] = {ee4.x, ee4.y, ee4.z, ee4.w};
            f32x4 dist4;
            #pragma unroll
            for (int r = 0; r < 4; ++r) {
                float dv = fmaf(accA[r] + accB[r], -2.f, xx + eev[r]);
                dist4[r] = dv;
                if (dv < m1) { m2 = m1; m1 = dv; k1 = kb + r; }   // k ascending
                else if (dv < m2) m2 = dv;
            }
            *(f32x4*)(drow + kb) = dist4;    // one dwordx4 store per kt
        }
        if (c < 7) STAGE_WRITE((c + 1) & 1);
        __syncthreads();                     // buffer handoff (also final vmcnt drain)
    }

    // ---- per-row argmin across the 4 k-lanes + rare candidate-only fp64 refine ----
    float bv = m1; int bk = k1;
    {
        float ov = __shfl_xor(bv, 16, 64); int ok = __shfl_xor(bk, 16, 64);
        if (ov < bv || (ov == bv && ok < bk)) { bv = ov; bk = ok; }
        ov = __shfl_xor(bv, 32, 64); ok = __shfl_xor(bk, 32, 64);
        if (ov < bv || (ov == bv && ok < bk)) { bv = ov; bk = ok; }
    }
    const float thr = bv + EPS;
    const unsigned long long gmask = 0x0001000100010001ULL << (l & 15);
    unsigned long long b1 = __ballot(m1 <= thr);
    unsigned long long b2 = __ballot(m2 <= thr);
    int enc = bk; float lossv = bv;
    if (__popcll(b1 & gmask) > 1 || (b2 & gmask) != 0ULL) {   // group-coherent branch
        const float* dr   = drow + (l >> 4) * 128;
        const float* xcol = x + xbase + myw;
        double bestv = 1e300; int bestk = 0x7fffffff;
        #pragma unroll 1
        for (int c4 = 0; c4 < 32; ++c4) {
            float4 dv4 = *(const float4*)(dr + c4 * 4);
            float dvv[4] = {dv4.x, dv4.y, dv4.z, dv4.w};
            #pragma unroll 1
            for (int j = 0; j < 4; ++j) {
                if (dvv[j] <= thr) {
                    int k = (l >> 4) * 128 + c4 * 4 + j;
                    const float* er = emb + k * 64;
                    double s = 0.0;
                    #pragma unroll 4
                    for (int d = 0; d < 64; ++d) {
                        double df = (double)xcol[(size_t)d * 4096] - (double)er[d];
                        s += df * df;
                    }
                    if (s < bestv) { bestv = s; bestk = k; }  // ascending k, strict <
                }
            }
        }
        double ov = __shfl_xor(bestv, 16, 64); int ok = __shfl_xor(bestk, 16, 64);
        if (ov < bestv || (ov == bestv && ok < bestk)) { bestv = ov; bestk = ok; }
        ov = __shfl_xor(bestv, 32, 64); ok = __shfl_xor(bestk, 32, 64);
        if (ov < bestv || (ov == bestv && ok < bestk)) { bestv = ov; bestk = ok; }
        enc = bestk;
        if (l < 16 && enc != bk) lossv = drow[enc];
    }
    if (l < 16) {
        enc_s[myw] = enc;
        out_enc[n_base + myw] = (float)enc;
    }
    float lc = (l < 16) ? lossv : 0.f;       // row's (q-x)^2 sum == dist[row][enc]
    #pragma unroll
    for (int m = 32; m >= 1; m >>= 1) lc += __shfl_down(lc, m, 64);
    if (l == 0) red_s[wv] = lc;
    __syncthreads();
    if (t == 0)
        atomicAdd(out_loss, (red_s[0] + red_s[1] + red_s[2] + red_s[3]) * (1.0f / 8388608.0f));

    // ---- quantized gather (codebook L2-resident) + coalesced store ----
    {
        const int w  = t & 63;
        const int dg = t >> 6;               // d = dg*16..+15
        const int e  = enc_s[w];
        const float* er = emb + e * 64 + dg * 16;
        float* qp = out_q + xbase + (size_t)(dg * 16) * 4096 + w;
        #pragma unroll
        for (int qi = 0; qi < 4; ++qi) {
            float4 q4 = *(const float4*)(er + qi * 4);
            qp[(size_t)(qi * 4 + 0) * 4096] = q4.x;
            qp[(size_t)(qi * 4 + 1) * 4096] = q4.y;
            qp[(size_t)(qi * 4 + 2) * 4096] = q4.z;
            qp[(size_t)(qi * 4 + 3) * 4096] = q4.w;
        }
    }
}

extern "C" void kernel_launch(void* const* d_in, const int* in_sizes, int n_in,
                              void* d_out, int out_size, void* d_ws, size_t ws_size,
                              hipStream_t stream) {
    const float* x   = (const float*)d_in[0];   // [32,64,64,64]
    const float* emb = (const float*)d_in[1];   // [512,64]

    float* out_q    = (float*)d_out;            // 8388608
    float* out_enc  = out_q + 8388608;          // 131072
    float* out_dist = out_enc + 131072;         // 67108864
    float* out_loss = out_dist + 67108864;      // 1

    unsigned short* whi = (unsigned short*)d_ws;        // 512*64 bf16 hi   (64 KB)
    unsigned short* wlo = whi + 32768;                  // 512*64 bf16 lo   (64 KB)
    float*          wee = (float*)(whi + 65536);        // 512 norms        (2 KB)

    hipMemsetAsync(out_loss, 0, sizeof(float), stream);
    prep_kernel<<<8, 64, 0, stream>>>(emb, whi, wlo, wee);
    vq_kernel<<<2048, 256, 0, stream>>>(x, emb, whi, wlo, wee,
                                        out_q, out_enc, out_dist, out_loss);
}